// Round 16
// baseline (132.980 us; speedup 1.0000x reference)
//
#include <hip/hip_runtime.h>
#include <stdint.h>

#define N_NODES 50000
#define IN_CH   128
#define HID     128
#define OUT_CH  64

#define CBITS 8
#define NCB   196                         // coarse buckets (dst>>8)
#define CAP   8192                        // per-bucket capacity in ebuf2/ebuf16
#define APB   4096                        // edges per pass-A / deg block

#define XPAD  136                         // ushorts per LDS row (128 + 8 pad)
#define G1BLK 782                         // gemm tiles: ceil(50000/64)

typedef unsigned int   uint32;
typedef unsigned short ushort16;
typedef __attribute__((ext_vector_type(8))) short short8;   // 8 bf16
typedef __attribute__((ext_vector_type(4))) float f32x4;

static __device__ __forceinline__ ushort16 f32_to_bf16(float f) {
    uint32 u = __float_as_uint(f);
    u = (u + 0x7fffu + ((u >> 16) & 1u)) >> 16;   // RNE
    return (ushort16)u;
}
static __device__ __forceinline__ float bf16lo_to_f32(uint32 u) {
    return __uint_as_float(u << 16);
}
static __device__ __forceinline__ float bf16hi_to_f32(uint32 u) {
    return __uint_as_float(u & 0xffff0000u);
}
#define RLI(v, l) __builtin_amdgcn_readlane((v), (l))

// ---------------- prep: W1^T/W2^T -> bf16, zero gcur + degi ----------------
__global__ __launch_bounds__(256) void prep_kernel(
    const float* __restrict__ W1, const float* __restrict__ W2,
    ushort16* __restrict__ w1t, ushort16* __restrict__ w2t,
    int* __restrict__ gcur, int* __restrict__ degi) {
    const int t = threadIdx.x;
    const int b = blockIdx.x;
    if (b == 64) {                          // zero bucket counters
        if (t < NCB) gcur[t] = 0;
        return;
    }
    if (b >= 65) {                          // zero degi
        int i = (b - 65) * 256 + t;
        if (i < N_NODES) degi[i] = 0;
        return;
    }
    int i = b * 256 + t;
    if (i < 128 * 128) {
        int k = i >> 7, n = i & 127;
        w1t[n * 128 + k] = f32_to_bf16(W1[k * 128 + n]);
    }
    if (i < 128 * 64) {
        int k = i >> 6, n = i & 63;
        w2t[n * 128 + k] = f32_to_bf16(W2[k * 64 + n]);
    }
}

// ---------------- build1: passA (blocks < nA) ∥ deg_count (blocks >= nA) ----------------
__global__ __launch_bounds__(256) void build1_kernel(
    const int* __restrict__ src, const int* __restrict__ dst,
    int* __restrict__ gcur, uint32* __restrict__ ebuf2, int E, int nA,
    int* __restrict__ degi) {
    __shared__ __align__(16) char smem[20992];   // passA: 4*1KB + 16KB obuf
    const int t = threadIdx.x;

    if ((int)blockIdx.x >= nA) {
        // ---- deg_count: same validity predicate as passA ----
        const int e0 = ((int)blockIdx.x - nA) * APB;
        #pragma unroll
        for (int j = 0; j < 16; ++j) {
            int i = e0 + t + 256 * j;
            if (i < E) {
                int s = src[i], d = dst[i];
                if ((unsigned)d < N_NODES && (unsigned)s < N_NODES)
                    atomicAdd(&degi[d], 1);
            }
        }
        return;
    }

    // ---- passA: coarse partition edges by dst>>8 into ebuf2 (src | dst<<16) ----
    int* hist = (int*)smem;
    int* excl = hist + 256;
    int* fcur = excl + 256;
    int* gbase = fcur + 256;
    uint32* obuf = (uint32*)(gbase + 256);   // APB entries

    const int e0 = blockIdx.x * APB;
    const int nv = min(APB, E - e0);

    hist[t] = 0;
    __syncthreads();

    uint32 u[16];
    #pragma unroll
    for (int j = 0; j < 16; ++j) {
        int i = t + 256 * j;
        u[j] = 0xffffffffu;
        if (i < nv) {
            int e = e0 + i;
            int s = src[e], d = dst[e];
            if ((unsigned)d < N_NODES && (unsigned)s < N_NODES) {
                u[j] = (uint32)s | ((uint32)d << 16);
                atomicAdd(&hist[(unsigned)d >> CBITS], 1);
            }
        }
    }
    __syncthreads();

    excl[t] = hist[t];
    __syncthreads();
    #pragma unroll
    for (int off = 1; off < 256; off <<= 1) {
        int v = (t >= off) ? excl[t - off] : 0;
        __syncthreads();
        excl[t] += v;
        __syncthreads();
    }
    int myexcl = excl[t] - hist[t];
    int gb = 0;
    if (hist[t] > 0) gb = t * CAP + atomicAdd(&gcur[t], hist[t]);
    __syncthreads();
    excl[t] = myexcl;
    fcur[t] = myexcl;
    gbase[t] = gb;
    __syncthreads();

    #pragma unroll
    for (int j = 0; j < 16; ++j) {
        if (u[j] != 0xffffffffu) {
            int b = u[j] >> (16 + CBITS);
            int pos = atomicAdd(&fcur[b], 1);
            obuf[pos] = u[j];
        }
    }
    __syncthreads();

    for (int i = t; i < nv; i += 256) {
        uint32 v = obuf[i];
        int b = v >> (16 + CBITS);
        int gpos = gbase[b] + (i - excl[b]);
        if (gpos < (b + 1) * CAP) ebuf2[gpos] = v;   // capacity guard
    }
}

// ---------------- build2: passB (blocks < NCB) ∥ gemm1s (blocks >= NCB) ----------------
// gemm1s: h1s = bf16((x @ W1) * dinv[row]) with dinv from completed degi.
__global__ __launch_bounds__(256) void build2_kernel(
    const uint32* __restrict__ ebuf2, const int* __restrict__ gcur,
    ushort16* __restrict__ ebuf16, int* __restrict__ offs,
    const int* __restrict__ degi, float* __restrict__ dinv,
    const float* __restrict__ x, const ushort16* __restrict__ w1t,
    ushort16* __restrict__ h1s) {
    __shared__ __align__(16) char smem[53248];
    const int t = threadIdx.x;

    if ((int)blockIdx.x >= NCB) {
        // ---- gemm1s ----
        ushort16* xs = (ushort16*)smem;                       // 64*XPAD
        ushort16* wt = (ushort16*)(smem + 64 * XPAD * 2);     // 128*XPAD
        const int block_row = ((int)blockIdx.x - NCB) * 64;

        {
            const uint4* g = (const uint4*)w1t;
            #pragma unroll
            for (int j = 0; j < 8; ++j) {
                int idx = t + 256 * j;
                int row = idx >> 4, c = idx & 15;
                uint4 v = g[idx];
                *(uint4*)&wt[row * XPAD + c * 8] = v;
            }
        }
        {
            #pragma unroll
            for (int j = 0; j < 8; ++j) {
                int idx = t + 256 * j;            // 0..2047 float4s
                int row = idx >> 5, c4 = idx & 31;
                int gr = block_row + row; if (gr >= N_NODES) gr = N_NODES - 1;
                float4 v = *(const float4*)(x + (size_t)gr * IN_CH + c4 * 4);
                uint32 p0 = (uint32)f32_to_bf16(v.x) | ((uint32)f32_to_bf16(v.y) << 16);
                uint32 p1 = (uint32)f32_to_bf16(v.z) | ((uint32)f32_to_bf16(v.w) << 16);
                uint32* dp = (uint32*)&xs[row * XPAD + c4 * 4];
                dp[0] = p0; dp[1] = p1;
            }
        }
        __syncthreads();

        const int wv = t >> 6, lane = t & 63;
        const int r16 = lane & 15, kq = lane >> 4;
        f32x4 acc[8];
        #pragma unroll
        for (int n = 0; n < 8; ++n) acc[n] = (f32x4){0.f, 0.f, 0.f, 0.f};

        const ushort16* xrow = &xs[(wv * 16 + r16) * XPAD + kq * 8];
        #pragma unroll
        for (int kk = 0; kk < 4; ++kk) {
            short8 a = *(const short8*)(xrow + kk * 32);
            #pragma unroll
            for (int n = 0; n < 8; ++n) {
                short8 b = *(const short8*)&wt[(n * 16 + r16) * XPAD + kk * 32 + kq * 8];
                acc[n] = __builtin_amdgcn_mfma_f32_16x16x32_bf16(a, b, acc[n], 0, 0, 0);
            }
        }

        #pragma unroll
        for (int j = 0; j < 4; ++j) {
            int gr = block_row + wv * 16 + kq * 4 + j;
            if (gr < N_NODES) {
                float dv = rsqrtf(1.0f + (float)degi[gr]);
                #pragma unroll
                for (int n = 0; n < 8; ++n)
                    h1s[(size_t)gr * HID + n * 16 + r16] = f32_to_bf16(acc[n][j] * dv);
            }
        }
        return;
    }

    // ---- passB: fine sort within bucket; emits ebuf16 + offs + dinv (degi already set) ----
    uint32*   sbuf = (uint32*)smem;                       // CAP u32
    ushort16* obuf = (ushort16*)(smem + CAP * 4);         // CAP u16
    int* fh = (int*)(smem + CAP * 4 + CAP * 2);
    int* fx = fh + 256;
    int* fc = fx + 256;
    int* gs = fc + 256;
    const int b = blockIdx.x;

    {
        int c = (t < NCB) ? min(gcur[t], CAP) : 0;
        gs[t] = c;
        __syncthreads();
        #pragma unroll
        for (int off = 1; off < 256; off <<= 1) {
            int v = (t >= off) ? gs[t - off] : 0;
            __syncthreads();
            gs[t] += v;
            __syncthreads();
        }
    }
    const int nb = min(gcur[b], CAP);
    const int obase = gs[b] - nb;
    __syncthreads();

    fh[t] = 0;
    __syncthreads();
    for (int i = t; i < nb; i += 256) {
        uint32 v = ebuf2[b * CAP + i];
        sbuf[i] = v;
        atomicAdd(&fh[(v >> 16) & 255], 1);
    }
    __syncthreads();

    fx[t] = fh[t];
    __syncthreads();
    #pragma unroll
    for (int off = 1; off < 256; off <<= 1) {
        int v = (t >= off) ? fx[t - off] : 0;
        __syncthreads();
        fx[t] += v;
        __syncthreads();
    }
    int ex = fx[t] - fh[t];
    fc[t] = ex;

    int n = b * 256 + t;
    if (n < N_NODES) {
        offs[n] = obase + ex;
        dinv[n] = rsqrtf(1.0f + (float)fh[t]);   // degi NOT rewritten (gemm1s reads it)
    }
    __syncthreads();

    for (int i = t; i < nb; i += 256) {
        uint32 v = sbuf[i];
        int nl = (v >> 16) & 255;
        int pos = atomicAdd(&fc[nl], 1);
        obuf[pos] = (ushort16)(v & 0xffffu);
    }
    __syncthreads();
    for (int i = t; i < nb; i += 256) ebuf16[obase + i] = obuf[i];
}

// ---------------- gather1 (weight-free, 8+4 deep): a1b = bf16(tanh(di*(sum h1s + self) + b1)) ----
__global__ __launch_bounds__(256) void gather1_kernel(
    const int* __restrict__ offs, const int* __restrict__ degi,
    const ushort16* __restrict__ ebuf16, const float* __restrict__ dinv,
    const ushort16* __restrict__ h1s, const float* __restrict__ b1,
    ushort16* __restrict__ a1b) {
    int node = blockIdx.x * 4 + (threadIdx.x >> 6);
    int lane = threadIdx.x & 63;
    if (node >= N_NODES) return;
    float di = dinv[node];
    int beg = offs[node];
    int cnt = degi[node];

    uint32 us = ((const uint32*)(h1s + (size_t)node * HID))[lane];
    float ax = bf16lo_to_f32(us);
    float ay = bf16hi_to_f32(us);

    for (int base = 0; base < cnt; base += 64) {
        int m = min(cnt - base, 64);
        int e_l = 0;
        if (lane < m) {
            e_l = (int)ebuf16[beg + base + lane];
            e_l = min(e_l, N_NODES - 1);          // harden vs poison under replay
        }
        int i = 0;
        for (; i + 8 <= m; i += 8) {
            int s0 = RLI(e_l, i),     s1 = RLI(e_l, i + 1);
            int s2 = RLI(e_l, i + 2), s3 = RLI(e_l, i + 3);
            int s4 = RLI(e_l, i + 4), s5 = RLI(e_l, i + 5);
            int s6 = RLI(e_l, i + 6), s7 = RLI(e_l, i + 7);
            uint32 u0 = ((const uint32*)(h1s + (size_t)s0 * HID))[lane];
            uint32 u1 = ((const uint32*)(h1s + (size_t)s1 * HID))[lane];
            uint32 u2 = ((const uint32*)(h1s + (size_t)s2 * HID))[lane];
            uint32 u3 = ((const uint32*)(h1s + (size_t)s3 * HID))[lane];
            uint32 u4 = ((const uint32*)(h1s + (size_t)s4 * HID))[lane];
            uint32 u5 = ((const uint32*)(h1s + (size_t)s5 * HID))[lane];
            uint32 u6 = ((const uint32*)(h1s + (size_t)s6 * HID))[lane];
            uint32 u7 = ((const uint32*)(h1s + (size_t)s7 * HID))[lane];
            ax += (bf16lo_to_f32(u0) + bf16lo_to_f32(u1))
                + (bf16lo_to_f32(u2) + bf16lo_to_f32(u3))
                + (bf16lo_to_f32(u4) + bf16lo_to_f32(u5))
                + (bf16lo_to_f32(u6) + bf16lo_to_f32(u7));
            ay += (bf16hi_to_f32(u0) + bf16hi_to_f32(u1))
                + (bf16hi_to_f32(u2) + bf16hi_to_f32(u3))
                + (bf16hi_to_f32(u4) + bf16hi_to_f32(u5))
                + (bf16hi_to_f32(u6) + bf16hi_to_f32(u7));
        }
        if (i + 4 <= m) {
            int s0 = RLI(e_l, i),     s1 = RLI(e_l, i + 1);
            int s2 = RLI(e_l, i + 2), s3 = RLI(e_l, i + 3);
            uint32 u0 = ((const uint32*)(h1s + (size_t)s0 * HID))[lane];
            uint32 u1 = ((const uint32*)(h1s + (size_t)s1 * HID))[lane];
            uint32 u2 = ((const uint32*)(h1s + (size_t)s2 * HID))[lane];
            uint32 u3 = ((const uint32*)(h1s + (size_t)s3 * HID))[lane];
            ax += (bf16lo_to_f32(u0) + bf16lo_to_f32(u1))
                + (bf16lo_to_f32(u2) + bf16lo_to_f32(u3));
            ay += (bf16hi_to_f32(u0) + bf16hi_to_f32(u1))
                + (bf16hi_to_f32(u2) + bf16hi_to_f32(u3));
            i += 4;
        }
        for (; i < m; ++i) {
            int s0 = RLI(e_l, i);
            uint32 u0 = ((const uint32*)(h1s + (size_t)s0 * HID))[lane];
            ax += bf16lo_to_f32(u0);
            ay += bf16hi_to_f32(u0);
        }
    }
    float2 bb = ((const float2*)b1)[lane];
    float tx = tanhf(di * ax + bb.x);
    float ty = tanhf(di * ay + bb.y);
    uint32 pk = (uint32)f32_to_bf16(tx) | ((uint32)f32_to_bf16(ty) << 16);
    ((uint32*)(a1b + (size_t)node * HID))[lane] = pk;
}

// ---------------- GEMM2 (MFMA): h2s = bf16((a1b @ W2) * dinv[row]) ----------------
__global__ __launch_bounds__(256) void gemm2_mfma_kernel(
    const ushort16* __restrict__ a1b, const ushort16* __restrict__ w2t,
    const float* __restrict__ dinv, ushort16* __restrict__ h2s) {
    __shared__ __align__(16) ushort16 xs[64 * XPAD];
    __shared__ __align__(16) ushort16 wt[64 * XPAD];
    const int tid = threadIdx.x;
    const int block_row = blockIdx.x * 64;

    {
        const uint4* g = (const uint4*)w2t;
        #pragma unroll
        for (int j = 0; j < 4; ++j) {
            int idx = tid + 256 * j;
            int row = idx >> 4, c = idx & 15;
            uint4 v = g[idx];
            *(uint4*)&wt[row * XPAD + c * 8] = v;
        }
    }
    {
        #pragma unroll
        for (int j = 0; j < 4; ++j) {
            int idx = tid + 256 * j;            // 0..1023 uint4s
            int row = idx >> 4, c = idx & 15;
            int gr = block_row + row; if (gr >= N_NODES) gr = N_NODES - 1;
            uint4 v = *(const uint4*)(a1b + (size_t)gr * HID + c * 8);
            *(uint4*)&xs[row * XPAD + c * 8] = v;
        }
    }
    __syncthreads();

    const int wv = tid >> 6, lane = tid & 63;
    const int r16 = lane & 15, kq = lane >> 4;
    f32x4 acc[4];
    #pragma unroll
    for (int n = 0; n < 4; ++n) acc[n] = (f32x4){0.f, 0.f, 0.f, 0.f};

    const ushort16* xrow = &xs[(wv * 16 + r16) * XPAD + kq * 8];
    #pragma unroll
    for (int kk = 0; kk < 4; ++kk) {
        short8 a = *(const short8*)(xrow + kk * 32);
        #pragma unroll
        for (int n = 0; n < 4; ++n) {
            short8 b = *(const short8*)&wt[(n * 16 + r16) * XPAD + kk * 32 + kq * 8];
            acc[n] = __builtin_amdgcn_mfma_f32_16x16x32_bf16(a, b, acc[n], 0, 0, 0);
        }
    }

    #pragma unroll
    for (int j = 0; j < 4; ++j) {
        int gr = block_row + wv * 16 + kq * 4 + j;
        if (gr < N_NODES) {
            float dv = dinv[gr];
            #pragma unroll
            for (int n = 0; n < 4; ++n)
                h2s[(size_t)gr * OUT_CH + n * 16 + r16] = f32_to_bf16(acc[n][j] * dv);
        }
    }
}

// ---------------- gather2 (weight-free, 8+4 deep): out = b2 + di*(sum h2s[s] + h2s[n]) ----
__global__ __launch_bounds__(256) void gather2_kernel(
    const int* __restrict__ offs, const int* __restrict__ degi,
    const ushort16* __restrict__ ebuf16, const float* __restrict__ dinv,
    const ushort16* __restrict__ h2s, const float* __restrict__ b2,
    float* __restrict__ out) {
    int node = blockIdx.x * 4 + (threadIdx.x >> 6);
    int lane = threadIdx.x & 63;
    if (node >= N_NODES) return;
    float di = dinv[node];
    int beg = offs[node];
    int cnt = degi[node];

    float acc = __uint_as_float(((uint32)h2s[(size_t)node * OUT_CH + lane]) << 16);

    for (int base = 0; base < cnt; base += 64) {
        int m = min(cnt - base, 64);
        int e_l = 0;
        if (lane < m) {
            e_l = (int)ebuf16[beg + base + lane];
            e_l = min(e_l, N_NODES - 1);          // harden vs poison under replay
        }
        int i = 0;
        for (; i + 8 <= m; i += 8) {
            int s0 = RLI(e_l, i),     s1 = RLI(e_l, i + 1);
            int s2 = RLI(e_l, i + 2), s3 = RLI(e_l, i + 3);
            int s4 = RLI(e_l, i + 4), s5 = RLI(e_l, i + 5);
            int s6 = RLI(e_l, i + 6), s7 = RLI(e_l, i + 7);
            float v0 = __uint_as_float(((uint32)h2s[(size_t)s0 * OUT_CH + lane]) << 16);
            float v1 = __uint_as_float(((uint32)h2s[(size_t)s1 * OUT_CH + lane]) << 16);
            float v2 = __uint_as_float(((uint32)h2s[(size_t)s2 * OUT_CH + lane]) << 16);
            float v3 = __uint_as_float(((uint32)h2s[(size_t)s3 * OUT_CH + lane]) << 16);
            float v4 = __uint_as_float(((uint32)h2s[(size_t)s4 * OUT_CH + lane]) << 16);
            float v5 = __uint_as_float(((uint32)h2s[(size_t)s5 * OUT_CH + lane]) << 16);
            float v6 = __uint_as_float(((uint32)h2s[(size_t)s6 * OUT_CH + lane]) << 16);
            float v7 = __uint_as_float(((uint32)h2s[(size_t)s7 * OUT_CH + lane]) << 16);
            acc += ((v0 + v1) + (v2 + v3)) + ((v4 + v5) + (v6 + v7));
        }
        if (i + 4 <= m) {
            int s0 = RLI(e_l, i),     s1 = RLI(e_l, i + 1);
            int s2 = RLI(e_l, i + 2), s3 = RLI(e_l, i + 3);
            float v0 = __uint_as_float(((uint32)h2s[(size_t)s0 * OUT_CH + lane]) << 16);
            float v1 = __uint_as_float(((uint32)h2s[(size_t)s1 * OUT_CH + lane]) << 16);
            float v2 = __uint_as_float(((uint32)h2s[(size_t)s2 * OUT_CH + lane]) << 16);
            float v3 = __uint_as_float(((uint32)h2s[(size_t)s3 * OUT_CH + lane]) << 16);
            acc += (v0 + v1) + (v2 + v3);
            i += 4;
        }
        for (; i < m; ++i) {
            int s0 = RLI(e_l, i);
            acc += __uint_as_float(((uint32)h2s[(size_t)s0 * OUT_CH + lane]) << 16);
        }
    }
    out[(size_t)node * OUT_CH + lane] = b2[lane] + di * acc;
}

extern "C" void kernel_launch(void* const* d_in, const int* in_sizes, int n_in,
                              void* d_out, int out_size, void* d_ws, size_t ws_size,
                              hipStream_t stream) {
    const float* x  = (const float*)d_in[0];
    const int*   ei = (const int*)d_in[1];
    const float* W1 = (const float*)d_in[2];
    const float* b1 = (const float*)d_in[3];
    const float* W2 = (const float*)d_in[4];
    const float* b2 = (const float*)d_in[5];
    float* out = (float*)d_out;

    const int E = in_sizes[1] / 2;   // edge_index is [2, E]
    const int* src = ei;
    const int* dst = ei + E;
    const int nA = (E + APB - 1) / APB;   // passA blocks
    const int nD = (E + APB - 1) / APB;   // deg_count blocks

    // workspace layout
    float* dinv   = (float*)d_ws;                 // N
    int* degi     = (int*)(dinv + N_NODES);       // N
    int* offs     = degi + N_NODES;               // N
    int* gcur     = offs + N_NODES;               // NCB
    ushort16* w1t = (ushort16*)(gcur + NCB);      // 128*128
    ushort16* w2t = w1t + 128 * 128;              // 64*128
    ushort16* ebuf16 = w2t + 64 * 128;            // NCB*CAP (u16) — worst-case sized
    uintptr_t p   = (uintptr_t)(ebuf16 + (size_t)NCB * CAP);
    p = (p + 15) & ~(uintptr_t)15;
    ushort16* a1b = (ushort16*)p;                     // N*128 bf16
    uint32* ebuf2 = (uint32*)a1b;                     // NCB*CAP u32, aliases a1b (used before it)
    ushort16* h1s = a1b + (size_t)N_NODES * HID;      // N*128 bf16 (dinv-prescaled)
    ushort16* h2s = h1s + (size_t)N_NODES * HID;      // N*64 bf16 (dinv-prescaled)

    prep_kernel<<<65 + (N_NODES + 255) / 256, 256, 0, stream>>>(W1, W2, w1t, w2t, gcur, degi);
    build1_kernel<<<nA + nD, 256, 0, stream>>>(src, dst, gcur, ebuf2, E, nA, degi);
    build2_kernel<<<NCB + G1BLK, 256, 0, stream>>>(ebuf2, gcur, ebuf16, offs, degi, dinv,
                                                   x, w1t, h1s);
    gather1_kernel<<<(N_NODES + 3) / 4, 256, 0, stream>>>(offs, degi, ebuf16, dinv, h1s, b1, a1b);
    gemm2_mfma_kernel<<<G1BLK, 256, 0, stream>>>(a1b, w2t, dinv, h2s);
    gather2_kernel<<<(N_NODES + 3) / 4, 256, 0, stream>>>(offs, degi, ebuf16, dinv, h2s, b2, out);
}

// Round 17
// 108.060 us; speedup vs baseline: 1.2306x; 1.2306x over previous
//
#include <hip/hip_runtime.h>
#include <stdint.h>

#define N_NODES 50000
#define IN_CH   128
#define HID     128
#define OUT_CH  64

#define CBITS 8
#define NCB   196                         // coarse buckets (dst>>8)
#define CAP   8192                        // per-bucket capacity in ebuf2/ebuf16
#define APB   4096                        // edges per pass-A block

#define XPAD  136                         // ushorts per LDS row (128 + 8 pad)
#define G1BLK 782                         // gemm tiles: ceil(50000/64)

typedef unsigned int   uint32;
typedef unsigned short ushort16;
typedef __attribute__((ext_vector_type(8))) short short8;   // 8 bf16
typedef __attribute__((ext_vector_type(4))) float f32x4;

static __device__ __forceinline__ ushort16 f32_to_bf16(float f) {
    uint32 u = __float_as_uint(f);
    u = (u + 0x7fffu + ((u >> 16) & 1u)) >> 16;   // RNE
    return (ushort16)u;
}
static __device__ __forceinline__ float bf16lo_to_f32(uint32 u) {
    return __uint_as_float(u << 16);
}
static __device__ __forceinline__ float bf16hi_to_f32(uint32 u) {
    return __uint_as_float(u & 0xffff0000u);
}
#define RLI(v, l) __builtin_amdgcn_readlane((v), (l))
#define RLF(v, l) __uint_as_float((uint32)__builtin_amdgcn_readlane((int)__float_as_uint(v), (l)))

// ---------------- prep: W1^T/W2^T -> bf16, zero gcur ----------------
__global__ __launch_bounds__(256) void prep_kernel(
    const float* __restrict__ W1, const float* __restrict__ W2,
    ushort16* __restrict__ w1t, ushort16* __restrict__ w2t,
    int* __restrict__ gcur) {
    const int t = threadIdx.x;
    if (blockIdx.x == 64) {                 // zero bucket counters
        if (t < NCB) gcur[t] = 0;
        return;
    }
    int i = blockIdx.x * 256 + t;
    if (i < 128 * 128) {
        int k = i >> 7, n = i & 127;
        w1t[n * 128 + k] = f32_to_bf16(W1[k * 128 + n]);
    }
    if (i < 128 * 64) {
        int k = i >> 6, n = i & 63;
        w2t[n * 128 + k] = f32_to_bf16(W2[k * 64 + n]);
    }
}

// ---------------- build1: passA (blocks < nA) ∥ gemm1 (blocks >= nA) ----------------
__global__ __launch_bounds__(256) void build1_kernel(
    const int* __restrict__ src, const int* __restrict__ dst,
    int* __restrict__ gcur, uint32* __restrict__ ebuf2, int E, int nA,
    const float* __restrict__ x, const ushort16* __restrict__ w1t,
    ushort16* __restrict__ h1b) {
    __shared__ __align__(16) char smem[52224];   // gemm1 needs exactly 52224
    const int t = threadIdx.x;

    if ((int)blockIdx.x >= nA) {
        // ---- gemm1: h1b = bf16(x @ W1), tile 64 rows x 128 cols ----
        ushort16* xs = (ushort16*)smem;                       // 64*XPAD
        ushort16* wt = (ushort16*)(smem + 64 * XPAD * 2);     // 128*XPAD
        const int block_row = ((int)blockIdx.x - nA) * 64;

        {
            const uint4* g = (const uint4*)w1t;
            #pragma unroll
            for (int j = 0; j < 8; ++j) {
                int idx = t + 256 * j;
                int row = idx >> 4, c = idx & 15;
                uint4 v = g[idx];
                *(uint4*)&wt[row * XPAD + c * 8] = v;
            }
        }
        {
            #pragma unroll
            for (int j = 0; j < 8; ++j) {
                int idx = t + 256 * j;            // 0..2047 float4s
                int row = idx >> 5, c4 = idx & 31;
                int gr = block_row + row; if (gr >= N_NODES) gr = N_NODES - 1;
                float4 v = *(const float4*)(x + (size_t)gr * IN_CH + c4 * 4);
                uint32 p0 = (uint32)f32_to_bf16(v.x) | ((uint32)f32_to_bf16(v.y) << 16);
                uint32 p1 = (uint32)f32_to_bf16(v.z) | ((uint32)f32_to_bf16(v.w) << 16);
                uint32* dp = (uint32*)&xs[row * XPAD + c4 * 4];
                dp[0] = p0; dp[1] = p1;
            }
        }
        __syncthreads();

        const int wv = t >> 6, lane = t & 63;
        const int r16 = lane & 15, kq = lane >> 4;
        f32x4 acc[8];
        #pragma unroll
        for (int n = 0; n < 8; ++n) acc[n] = (f32x4){0.f, 0.f, 0.f, 0.f};

        const ushort16* xrow = &xs[(wv * 16 + r16) * XPAD + kq * 8];
        #pragma unroll
        for (int kk = 0; kk < 4; ++kk) {
            short8 a = *(const short8*)(xrow + kk * 32);
            #pragma unroll
            for (int n = 0; n < 8; ++n) {
                short8 b = *(const short8*)&wt[(n * 16 + r16) * XPAD + kk * 32 + kq * 8];
                acc[n] = __builtin_amdgcn_mfma_f32_16x16x32_bf16(a, b, acc[n], 0, 0, 0);
            }
        }

        #pragma unroll
        for (int n = 0; n < 8; ++n) {
            #pragma unroll
            for (int j = 0; j < 4; ++j) {
                int gr = block_row + wv * 16 + kq * 4 + j;
                if (gr < N_NODES)
                    h1b[(size_t)gr * HID + n * 16 + r16] = f32_to_bf16(acc[n][j]);
            }
        }
        return;
    }

    // ---- passA: coarse partition edges by dst>>8 into ebuf2 (src | dst<<16) ----
    int* hist = (int*)smem;
    int* excl = hist + 256;
    int* fcur = excl + 256;
    int* gbase = fcur + 256;
    uint32* obuf = (uint32*)(gbase + 256);   // APB entries (16 KB); total 20.5 KB

    const int e0 = blockIdx.x * APB;
    const int nv = min(APB, E - e0);

    hist[t] = 0;
    __syncthreads();

    uint32 u[16];
    #pragma unroll
    for (int j = 0; j < 16; ++j) {
        int i = t + 256 * j;
        u[j] = 0xffffffffu;
        if (i < nv) {
            int e = e0 + i;
            int s = src[e], d = dst[e];
            if ((unsigned)d < N_NODES && (unsigned)s < N_NODES) {
                u[j] = (uint32)s | ((uint32)d << 16);
                atomicAdd(&hist[(unsigned)d >> CBITS], 1);
            }
        }
    }
    __syncthreads();

    excl[t] = hist[t];
    __syncthreads();
    #pragma unroll
    for (int off = 1; off < 256; off <<= 1) {
        int v = (t >= off) ? excl[t - off] : 0;
        __syncthreads();
        excl[t] += v;
        __syncthreads();
    }
    int myexcl = excl[t] - hist[t];
    int gb = 0;
    if (hist[t] > 0) gb = t * CAP + atomicAdd(&gcur[t], hist[t]);
    __syncthreads();
    excl[t] = myexcl;
    fcur[t] = myexcl;
    gbase[t] = gb;
    __syncthreads();

    #pragma unroll
    for (int j = 0; j < 16; ++j) {
        if (u[j] != 0xffffffffu) {
            int b = u[j] >> (16 + CBITS);
            int pos = atomicAdd(&fcur[b], 1);
            obuf[pos] = u[j];
        }
    }
    __syncthreads();

    for (int i = t; i < nv; i += 256) {
        uint32 v = obuf[i];
        int b = v >> (16 + CBITS);
        int gpos = gbase[b] + (i - excl[b]);
        if (gpos < (b + 1) * CAP) ebuf2[gpos] = v;   // capacity guard
    }
}

// ---------------- build2: passB — fine sort within bucket ----------------
__global__ __launch_bounds__(256) void build2_kernel(
    const uint32* __restrict__ ebuf2, const int* __restrict__ gcur,
    ushort16* __restrict__ ebuf16, int* __restrict__ offs,
    int* __restrict__ degi, float* __restrict__ dinv) {
    __shared__ __align__(16) char smem[53248];   // sbuf32K+obuf16K+fh/fx/fc/gs 4K
    uint32*   sbuf = (uint32*)smem;                       // CAP u32
    ushort16* obuf = (ushort16*)(smem + CAP * 4);         // CAP u16
    int* fh = (int*)(smem + CAP * 4 + CAP * 2);
    int* fx = fh + 256;
    int* fc = fx + 256;
    int* gs = fc + 256;
    const int b = blockIdx.x, t = threadIdx.x;

    {
        int c = (t < NCB) ? min(gcur[t], CAP) : 0;
        gs[t] = c;
        __syncthreads();
        #pragma unroll
        for (int off = 1; off < 256; off <<= 1) {
            int v = (t >= off) ? gs[t - off] : 0;
            __syncthreads();
            gs[t] += v;
            __syncthreads();
        }
    }
    const int nb = min(gcur[b], CAP);
    const int obase = gs[b] - nb;
    __syncthreads();

    fh[t] = 0;
    __syncthreads();
    for (int i = t; i < nb; i += 256) {
        uint32 v = ebuf2[b * CAP + i];
        sbuf[i] = v;
        atomicAdd(&fh[(v >> 16) & 255], 1);
    }
    __syncthreads();

    fx[t] = fh[t];
    __syncthreads();
    #pragma unroll
    for (int off = 1; off < 256; off <<= 1) {
        int v = (t >= off) ? fx[t - off] : 0;
        __syncthreads();
        fx[t] += v;
        __syncthreads();
    }
    int ex = fx[t] - fh[t];
    fc[t] = ex;

    int n = b * 256 + t;
    if (n < N_NODES) {
        degi[n] = fh[t];
        offs[n] = obase + ex;
        dinv[n] = rsqrtf(1.0f + (float)fh[t]);
    }
    __syncthreads();

    for (int i = t; i < nb; i += 256) {
        uint32 v = sbuf[i];
        int nl = (v >> 16) & 255;
        int pos = atomicAdd(&fc[nl], 1);
        obuf[pos] = (ushort16)(v & 0xffffu);
    }
    __syncthreads();
    for (int i = t; i < nb; i += 256) ebuf16[obase + i] = obuf[i];
}

// ---------------- gather1 (fused act, 8+4 deep): a1b = bf16(tanh(Ahat*h1 + b1)) ----------------
__global__ __launch_bounds__(256) void gather1_kernel(
    const int* __restrict__ offs, const int* __restrict__ degi,
    const ushort16* __restrict__ ebuf16, const float* __restrict__ dinv,
    const ushort16* __restrict__ h1b, const float* __restrict__ b1,
    ushort16* __restrict__ a1b) {
    int node = blockIdx.x * 4 + (threadIdx.x >> 6);
    int lane = threadIdx.x & 63;
    if (node >= N_NODES) return;
    float di = dinv[node];
    int beg = offs[node];
    int cnt = degi[node];

    uint32 us = ((const uint32*)(h1b + (size_t)node * HID))[lane];
    float ax = bf16lo_to_f32(us) * di * di;
    float ay = bf16hi_to_f32(us) * di * di;

    for (int base = 0; base < cnt; base += 64) {
        int m = min(cnt - base, 64);
        int e_l = 0; float w_l = 0.f;
        if (lane < m) {
            e_l = (int)ebuf16[beg + base + lane];
            e_l = min(e_l, N_NODES - 1);          // harden vs poison under replay
            w_l = dinv[e_l] * di;
        }
        int i = 0;
        for (; i + 8 <= m; i += 8) {
            int s0 = RLI(e_l, i),     s1 = RLI(e_l, i + 1);
            int s2 = RLI(e_l, i + 2), s3 = RLI(e_l, i + 3);
            int s4 = RLI(e_l, i + 4), s5 = RLI(e_l, i + 5);
            int s6 = RLI(e_l, i + 6), s7 = RLI(e_l, i + 7);
            float w0 = RLF(w_l, i),     w1 = RLF(w_l, i + 1);
            float w2 = RLF(w_l, i + 2), w3 = RLF(w_l, i + 3);
            float w4 = RLF(w_l, i + 4), w5 = RLF(w_l, i + 5);
            float w6 = RLF(w_l, i + 6), w7 = RLF(w_l, i + 7);
            uint32 u0 = ((const uint32*)(h1b + (size_t)s0 * HID))[lane];
            uint32 u1 = ((const uint32*)(h1b + (size_t)s1 * HID))[lane];
            uint32 u2 = ((const uint32*)(h1b + (size_t)s2 * HID))[lane];
            uint32 u3 = ((const uint32*)(h1b + (size_t)s3 * HID))[lane];
            uint32 u4 = ((const uint32*)(h1b + (size_t)s4 * HID))[lane];
            uint32 u5 = ((const uint32*)(h1b + (size_t)s5 * HID))[lane];
            uint32 u6 = ((const uint32*)(h1b + (size_t)s6 * HID))[lane];
            uint32 u7 = ((const uint32*)(h1b + (size_t)s7 * HID))[lane];
            ax += bf16lo_to_f32(u0) * w0 + bf16lo_to_f32(u1) * w1
                + bf16lo_to_f32(u2) * w2 + bf16lo_to_f32(u3) * w3
                + bf16lo_to_f32(u4) * w4 + bf16lo_to_f32(u5) * w5
                + bf16lo_to_f32(u6) * w6 + bf16lo_to_f32(u7) * w7;
            ay += bf16hi_to_f32(u0) * w0 + bf16hi_to_f32(u1) * w1
                + bf16hi_to_f32(u2) * w2 + bf16hi_to_f32(u3) * w3
                + bf16hi_to_f32(u4) * w4 + bf16hi_to_f32(u5) * w5
                + bf16hi_to_f32(u6) * w6 + bf16hi_to_f32(u7) * w7;
        }
        if (i + 4 <= m) {                        // 4-deep tail (cuts scalar iters ~2x)
            int s0 = RLI(e_l, i),     s1 = RLI(e_l, i + 1);
            int s2 = RLI(e_l, i + 2), s3 = RLI(e_l, i + 3);
            float w0 = RLF(w_l, i),     w1 = RLF(w_l, i + 1);
            float w2 = RLF(w_l, i + 2), w3 = RLF(w_l, i + 3);
            uint32 u0 = ((const uint32*)(h1b + (size_t)s0 * HID))[lane];
            uint32 u1 = ((const uint32*)(h1b + (size_t)s1 * HID))[lane];
            uint32 u2 = ((const uint32*)(h1b + (size_t)s2 * HID))[lane];
            uint32 u3 = ((const uint32*)(h1b + (size_t)s3 * HID))[lane];
            ax += bf16lo_to_f32(u0) * w0 + bf16lo_to_f32(u1) * w1
                + bf16lo_to_f32(u2) * w2 + bf16lo_to_f32(u3) * w3;
            ay += bf16hi_to_f32(u0) * w0 + bf16hi_to_f32(u1) * w1
                + bf16hi_to_f32(u2) * w2 + bf16hi_to_f32(u3) * w3;
            i += 4;
        }
        for (; i < m; ++i) {
            int s0 = RLI(e_l, i);
            float w0 = RLF(w_l, i);
            uint32 u0 = ((const uint32*)(h1b + (size_t)s0 * HID))[lane];
            ax += bf16lo_to_f32(u0) * w0;
            ay += bf16hi_to_f32(u0) * w0;
        }
    }
    float2 bb = ((const float2*)b1)[lane];
    float tx = tanhf(ax + bb.x);
    float ty = tanhf(ay + bb.y);
    uint32 pk = (uint32)f32_to_bf16(tx) | ((uint32)f32_to_bf16(ty) << 16);
    ((uint32*)(a1b + (size_t)node * HID))[lane] = pk;
}

// ---------------- GEMM2 (MFMA): h2s = bf16((a1b @ W2) * dinv[row]) ----------------
__global__ __launch_bounds__(256) void gemm2_mfma_kernel(
    const ushort16* __restrict__ a1b, const ushort16* __restrict__ w2t,
    const float* __restrict__ dinv, ushort16* __restrict__ h2s) {
    __shared__ __align__(16) ushort16 xs[64 * XPAD];
    __shared__ __align__(16) ushort16 wt[64 * XPAD];
    const int tid = threadIdx.x;
    const int block_row = blockIdx.x * 64;

    {
        const uint4* g = (const uint4*)w2t;
        #pragma unroll
        for (int j = 0; j < 4; ++j) {
            int idx = tid + 256 * j;
            int row = idx >> 4, c = idx & 15;
            uint4 v = g[idx];
            *(uint4*)&wt[row * XPAD + c * 8] = v;
        }
    }
    {
        #pragma unroll
        for (int j = 0; j < 4; ++j) {
            int idx = tid + 256 * j;            // 0..1023 uint4s
            int row = idx >> 4, c = idx & 15;
            int gr = block_row + row; if (gr >= N_NODES) gr = N_NODES - 1;
            uint4 v = *(const uint4*)(a1b + (size_t)gr * HID + c * 8);
            *(uint4*)&xs[row * XPAD + c * 8] = v;
        }
    }
    __syncthreads();

    const int wv = tid >> 6, lane = tid & 63;
    const int r16 = lane & 15, kq = lane >> 4;
    f32x4 acc[4];
    #pragma unroll
    for (int n = 0; n < 4; ++n) acc[n] = (f32x4){0.f, 0.f, 0.f, 0.f};

    const ushort16* xrow = &xs[(wv * 16 + r16) * XPAD + kq * 8];
    #pragma unroll
    for (int kk = 0; kk < 4; ++kk) {
        short8 a = *(const short8*)(xrow + kk * 32);
        #pragma unroll
        for (int n = 0; n < 4; ++n) {
            short8 b = *(const short8*)&wt[(n * 16 + r16) * XPAD + kk * 32 + kq * 8];
            acc[n] = __builtin_amdgcn_mfma_f32_16x16x32_bf16(a, b, acc[n], 0, 0, 0);
        }
    }

    #pragma unroll
    for (int j = 0; j < 4; ++j) {
        int gr = block_row + wv * 16 + kq * 4 + j;
        if (gr < N_NODES) {
            float dv = dinv[gr];
            #pragma unroll
            for (int n = 0; n < 4; ++n)
                h2s[(size_t)gr * OUT_CH + n * 16 + r16] = f32_to_bf16(acc[n][j] * dv);
        }
    }
}

// ---------------- gather2 (weight-free, 8+4 deep): out = b2 + di*(sum h2s[s] + h2s[n]) ----
__global__ __launch_bounds__(256) void gather2_kernel(
    const int* __restrict__ offs, const int* __restrict__ degi,
    const ushort16* __restrict__ ebuf16, const float* __restrict__ dinv,
    const ushort16* __restrict__ h2s, const float* __restrict__ b2,
    float* __restrict__ out) {
    int node = blockIdx.x * 4 + (threadIdx.x >> 6);
    int lane = threadIdx.x & 63;
    if (node >= N_NODES) return;
    float di = dinv[node];
    int beg = offs[node];
    int cnt = degi[node];

    float acc = __uint_as_float(((uint32)h2s[(size_t)node * OUT_CH + lane]) << 16);

    for (int base = 0; base < cnt; base += 64) {
        int m = min(cnt - base, 64);
        int e_l = 0;
        if (lane < m) {
            e_l = (int)ebuf16[beg + base + lane];
            e_l = min(e_l, N_NODES - 1);          // harden vs poison under replay
        }
        int i = 0;
        for (; i + 8 <= m; i += 8) {
            int s0 = RLI(e_l, i),     s1 = RLI(e_l, i + 1);
            int s2 = RLI(e_l, i + 2), s3 = RLI(e_l, i + 3);
            int s4 = RLI(e_l, i + 4), s5 = RLI(e_l, i + 5);
            int s6 = RLI(e_l, i + 6), s7 = RLI(e_l, i + 7);
            float v0 = __uint_as_float(((uint32)h2s[(size_t)s0 * OUT_CH + lane]) << 16);
            float v1 = __uint_as_float(((uint32)h2s[(size_t)s1 * OUT_CH + lane]) << 16);
            float v2 = __uint_as_float(((uint32)h2s[(size_t)s2 * OUT_CH + lane]) << 16);
            float v3 = __uint_as_float(((uint32)h2s[(size_t)s3 * OUT_CH + lane]) << 16);
            float v4 = __uint_as_float(((uint32)h2s[(size_t)s4 * OUT_CH + lane]) << 16);
            float v5 = __uint_as_float(((uint32)h2s[(size_t)s5 * OUT_CH + lane]) << 16);
            float v6 = __uint_as_float(((uint32)h2s[(size_t)s6 * OUT_CH + lane]) << 16);
            float v7 = __uint_as_float(((uint32)h2s[(size_t)s7 * OUT_CH + lane]) << 16);
            acc += ((v0 + v1) + (v2 + v3)) + ((v4 + v5) + (v6 + v7));
        }
        if (i + 4 <= m) {
            int s0 = RLI(e_l, i),     s1 = RLI(e_l, i + 1);
            int s2 = RLI(e_l, i + 2), s3 = RLI(e_l, i + 3);
            float v0 = __uint_as_float(((uint32)h2s[(size_t)s0 * OUT_CH + lane]) << 16);
            float v1 = __uint_as_float(((uint32)h2s[(size_t)s1 * OUT_CH + lane]) << 16);
            float v2 = __uint_as_float(((uint32)h2s[(size_t)s2 * OUT_CH + lane]) << 16);
            float v3 = __uint_as_float(((uint32)h2s[(size_t)s3 * OUT_CH + lane]) << 16);
            acc += (v0 + v1) + (v2 + v3);
            i += 4;
        }
        for (; i < m; ++i) {
            int s0 = RLI(e_l, i);
            acc += __uint_as_float(((uint32)h2s[(size_t)s0 * OUT_CH + lane]) << 16);
        }
    }
    out[(size_t)node * OUT_CH + lane] = b2[lane] + di * acc;
}

extern "C" void kernel_launch(void* const* d_in, const int* in_sizes, int n_in,
                              void* d_out, int out_size, void* d_ws, size_t ws_size,
                              hipStream_t stream) {
    const float* x  = (const float*)d_in[0];
    const int*   ei = (const int*)d_in[1];
    const float* W1 = (const float*)d_in[2];
    const float* b1 = (const float*)d_in[3];
    const float* W2 = (const float*)d_in[4];
    const float* b2 = (const float*)d_in[5];
    float* out = (float*)d_out;

    const int E = in_sizes[1] / 2;   // edge_index is [2, E]
    const int* src = ei;
    const int* dst = ei + E;
    const int nA = (E + APB - 1) / APB;

    // workspace layout
    float* dinv   = (float*)d_ws;                 // N
    int* degi     = (int*)(dinv + N_NODES);       // N
    int* offs     = degi + N_NODES;               // N
    int* gcur     = offs + N_NODES;               // NCB
    ushort16* w1t = (ushort16*)(gcur + NCB);      // 128*128
    ushort16* w2t = w1t + 128 * 128;              // 64*128
    ushort16* ebuf16 = w2t + 64 * 128;            // NCB*CAP (u16) — worst-case sized
    uintptr_t p   = (uintptr_t)(ebuf16 + (size_t)NCB * CAP);
    p = (p + 15) & ~(uintptr_t)15;
    ushort16* a1b = (ushort16*)p;                     // N*128 bf16
    uint32* ebuf2 = (uint32*)a1b;                     // NCB*CAP u32, aliases a1b (used before it)
    ushort16* h1b = a1b + (size_t)N_NODES * HID;      // N*128 bf16
    ushort16* h2s = h1b + (size_t)N_NODES * HID;      // N*64 bf16 (dinv-prescaled)

    prep_kernel<<<65, 256, 0, stream>>>(W1, W2, w1t, w2t, gcur);
    build1_kernel<<<nA + G1BLK, 256, 0, stream>>>(src, dst, gcur, ebuf2, E, nA,
                                                  x, w1t, h1b);
    build2_kernel<<<NCB, 256, 0, stream>>>(ebuf2, gcur, ebuf16, offs, degi, dinv);
    gather1_kernel<<<(N_NODES + 3) / 4, 256, 0, stream>>>(offs, degi, ebuf16, dinv, h1b, b1, a1b);
    gemm2_mfma_kernel<<<G1BLK, 256, 0, stream>>>(a1b, w2t, dinv, h2s);
    gather2_kernel<<<(N_NODES + 3) / 4, 256, 0, stream>>>(offs, degi, ebuf16, dinv, h2s, b2, out);
}